// Round 6
// baseline (405.008 us; speedup 1.0000x reference)
//
#include <hip/hip_runtime.h>
#include <hip/hip_bf16.h>
#include <cstdint>
#include <cstddef>

#define T0_ 512
#define TT_ 2048
#define WD_ 2048
#define NH_ 16
#define KH_ 4

typedef __attribute__((ext_vector_type(8))) short short8;
typedef __attribute__((ext_vector_type(4))) short short4v;
typedef __attribute__((ext_vector_type(4))) float f32x4;

#define AS1 __attribute__((address_space(1)))
#define AS3 __attribute__((address_space(3)))

__device__ __forceinline__ ushort f2bf(float x) {
  __hip_bfloat16 h = __float2bfloat16(x);
  ushort u; __builtin_memcpy(&u, &h, 2); return u;
}
__device__ __forceinline__ float bf2f(ushort u) {
  __hip_bfloat16 h; __builtin_memcpy(&h, &u, 2);
  return __bfloat162float(h);
}
__device__ __forceinline__ void g2l16(const ushort* g, AS3 ushort* s) {
  __builtin_amdgcn_global_load_lds((const AS1 uint32_t*)g, (AS3 uint32_t*)s, 16, 0, 0);
}

// ---------------------------------------------------------------------------
// x0/x1 (f32) -> xb (2048x2048 bf16)
__global__ __launch_bounds__(256) void convert_x(
    const float* __restrict__ x0, const float* __restrict__ x1, ushort* __restrict__ xb)
{
  const int i = blockIdx.x * 256 + threadIdx.x;
  const int e = i * 4;
  const int row = e >> 11, col = e & 2047;
  const float* src = (row < T0_) ? (x0 + (size_t)row * WD_ + col)
                                 : (x1 + (size_t)(row - T0_) * WD_ + col);
  const float4 v = *(const float4*)src;
  ushort4 o; o.x = f2bf(v.x); o.y = f2bf(v.y); o.z = f2bf(v.z); o.w = f2bf(v.w);
  *(ushort4*)(xb + e) = o;
}

// ---------------------------------------------------------------------------
// Generic 64x64 transpose-convert: up to 4 tensors, each (slabs, 2048, C) f32
// -> (slabs, C, 2048) bf16. grid (32, C/64, tensors*slabs), block 256.
struct P4 { const float* s[4]; ushort* d[4]; };

__global__ __launch_bounds__(256) void wtrans4(P4 p, int C, int slabs)
{
  __shared__ float tile[64][65];
  const int z = blockIdx.z;
  const int tz = z / slabs, sz = z % slabs;
  const float* in = p.s[tz] + (size_t)sz * 2048 * C;
  ushort* out = p.d[tz] + (size_t)sz * 2048 * C;
  const int r0 = blockIdx.x * 64, c0 = blockIdx.y * 64;
  const int t = threadIdx.x;
  const int lr = t >> 4, lc = (t & 15) * 4;
#pragma unroll
  for (int pp = 0; pp < 4; ++pp) {
    const float4 v = *(const float4*)(in + (size_t)(r0 + lr + 16 * pp) * C + c0 + lc);
    tile[lr + 16 * pp][lc + 0] = v.x; tile[lr + 16 * pp][lc + 1] = v.y;
    tile[lr + 16 * pp][lc + 2] = v.z; tile[lr + 16 * pp][lc + 3] = v.w;
  }
  __syncthreads();
  const int oc = t >> 4, rj = (t & 15) * 4;
#pragma unroll
  for (int pp = 0; pp < 4; ++pp) {
    const int orow = oc + 16 * pp;
    ushort4 o;
    o.x = f2bf(tile[rj + 0][orow]); o.y = f2bf(tile[rj + 1][orow]);
    o.z = f2bf(tile[rj + 2][orow]); o.w = f2bf(tile[rj + 3][orow]);
    *(ushort4*)(out + (size_t)(c0 + orow) * 2048 + r0 + rj) = o;
  }
}

// ---------------------------------------------------------------------------
// Shared MFMA GEMM core: 128x128 C tile, BK=32, 256 thr (4 waves 2x2).
__device__ __forceinline__ void gemm_core(
    const ushort* __restrict__ A, const ushort* __restrict__ Bt,
    int row0, int col0, ushort* As, ushort* Bs, f32x4 (&acc)[4][4])
{
  const int tid = threadIdx.x;
  const int w = tid >> 6, l = tid & 63, lq = l >> 4, lm = l & 15;
  const int wr = (w >> 1) * 64, wc = (w & 1) * 64;
  const ushort* Ag = A + (size_t)(row0 + (tid >> 2)) * WD_ + (tid & 3) * 8;
  const ushort* Bg = Bt + (size_t)(col0 + (tid >> 2)) * WD_ + (tid & 3) * 8;
  AS3 ushort* AsW = (AS3 ushort*)As + w * 512;
  AS3 ushort* BsW = (AS3 ushort*)Bs + w * 512;

  for (int k0 = 0; k0 < WD_; k0 += 32) {
    __syncthreads();
    g2l16(Ag + k0, AsW);
    g2l16(Ag + (size_t)64 * WD_ + k0, AsW + 2048);
    g2l16(Bg + k0, BsW);
    g2l16(Bg + (size_t)64 * WD_ + k0, BsW + 2048);
    __syncthreads();
    short8 af[4], bfr[4];
#pragma unroll
    for (int mi = 0; mi < 4; ++mi)
      af[mi] = *(const short8*)&As[(wr + mi * 16 + lm) * 32 + lq * 8];
#pragma unroll
    for (int ni = 0; ni < 4; ++ni)
      bfr[ni] = *(const short8*)&Bs[(wc + ni * 16 + lm) * 32 + lq * 8];
#pragma unroll
    for (int mi = 0; mi < 4; ++mi)
#pragma unroll
      for (int ni = 0; ni < 4; ++ni)
        acc[mi][ni] = __builtin_amdgcn_mfma_f32_16x16x32_bf16(af[mi], bfr[ni], acc[mi][ni], 0, 0, 0);
  }
}

// ---------------------------------------------------------------------------
// All projections in one launch. grid (40, 16):
//  bx<32: qg (bf16, ldc 4096) | bx 32..35: k->kcache f32 | bx 36..39: v->vcache f32
__global__ __launch_bounds__(256) void gemm_proj(
    const ushort* __restrict__ A,
    const ushort* __restrict__ qg0t, const ushort* __restrict__ qg1t,
    const ushort* __restrict__ k0t,  const ushort* __restrict__ k1t,
    const ushort* __restrict__ v0t,  const ushort* __restrict__ v1t,
    ushort* __restrict__ Cqg, float* __restrict__ kc, float* __restrict__ vc)
{
  __shared__ ushort As[4096], Bs[4096];
  const int bx = blockIdx.x;
  const int row0 = blockIdx.y * 128;
  const bool s1 = (row0 >= T0_);
  const ushort* Bt; int col0;
  float* Cf = nullptr; ushort* Cb = nullptr; int ldc;
  if (bx < 32) {
    Bt = s1 ? qg1t : qg0t; col0 = bx * 128; Cb = Cqg; ldc = 4096;
  } else if (bx < 36) {
    Bt = s1 ? k1t : k0t; col0 = (bx - 32) * 128; Cf = kc; ldc = 512;
  } else {
    Bt = s1 ? v1t : v0t; col0 = (bx - 36) * 128; Cf = vc; ldc = 512;
  }
  f32x4 acc[4][4];
#pragma unroll
  for (int mi = 0; mi < 4; ++mi)
#pragma unroll
    for (int ni = 0; ni < 4; ++ni) acc[mi][ni] = (f32x4){0.f, 0.f, 0.f, 0.f};
  gemm_core(A, Bt, row0, col0, As, Bs, acc);
  const int w = threadIdx.x >> 6, l = threadIdx.x & 63, lq = l >> 4, lm = l & 15;
  const int wr = (w >> 1) * 64, wc = (w & 1) * 64;
#pragma unroll
  for (int mi = 0; mi < 4; ++mi)
#pragma unroll
    for (int ni = 0; ni < 4; ++ni)
#pragma unroll
      for (int r = 0; r < 4; ++r) {
        const size_t rr = (size_t)row0 + wr + mi * 16 + lq * 4 + r;
        const size_t cc = (size_t)col0 + wc + ni * 16 + lm;
        if (Cb) Cb[rr * ldc + cc] = f2bf(acc[mi][ni][r]);
        else    Cf[rr * ldc + cc] = acc[mi][ni][r];
      }
}

// out projection: grid (16, 16); C f32 (t, 2048), weight by stream.
__global__ __launch_bounds__(256) void gemm_out(
    const ushort* __restrict__ A, const ushort* __restrict__ W0t,
    const ushort* __restrict__ W1t, float* __restrict__ C)
{
  __shared__ ushort As[4096], Bs[4096];
  const int row0 = blockIdx.y * 128, col0 = blockIdx.x * 128;
  const ushort* Bt = (row0 < T0_) ? W0t : W1t;
  f32x4 acc[4][4];
#pragma unroll
  for (int mi = 0; mi < 4; ++mi)
#pragma unroll
    for (int ni = 0; ni < 4; ++ni) acc[mi][ni] = (f32x4){0.f, 0.f, 0.f, 0.f};
  gemm_core(A, Bt, row0, col0, As, Bs, acc);
  const int w = threadIdx.x >> 6, l = threadIdx.x & 63, lq = l >> 4, lm = l & 15;
  const int wr = (w >> 1) * 64, wc = (w & 1) * 64;
#pragma unroll
  for (int mi = 0; mi < 4; ++mi)
#pragma unroll
    for (int ni = 0; ni < 4; ++ni)
#pragma unroll
      for (int r = 0; r < 4; ++r) {
        const size_t rr = (size_t)row0 + wr + mi * 16 + lq * 4 + r;
        const size_t cc = (size_t)col0 + wc + ni * 16 + lm;
        C[rr * 2048 + cc] = acc[mi][ni][r];
      }
}

// ---------------------------------------------------------------------------
// RMSNorm + RoPE (+ q scale).
__global__ __launch_bounds__(256) void postproc(
    ushort* __restrict__ qgb, float* __restrict__ kc, ushort* __restrict__ Kb,
    const int* __restrict__ positions,
    const float* __restrict__ qn0, const float* __restrict__ kn0,
    const float* __restrict__ qn1, const float* __restrict__ kn1)
{
  const int t = blockIdx.x;
  const int w = threadIdx.x >> 6, l = threadIdx.x & 63;
  const float pos = (float)positions[t];
  const bool str1 = (t >= T0_);
  const float* qn = str1 ? qn1 : qn0;
  const float* kn = str1 ? kn1 : kn0;
  const float kfreq = 13.815510557964274f / 32.0f;  // ln(1e6)/32
  const int h0 = 2 * l, h1 = 2 * l + 1;

  for (int r = w; r < NH_ + KH_; r += 4) {
    const bool isq = (r < NH_);
    float v0, v1; size_t bi; const float* sc;
    if (isq) {
      bi = ((size_t)t * NH_ + r) * 256;
      v0 = bf2f(qgb[bi + h0]); v1 = bf2f(qgb[bi + h1]); sc = qn;
    } else {
      bi = ((size_t)t * KH_ + (r - NH_)) * 128;
      v0 = kc[bi + h0]; v1 = kc[bi + h1]; sc = kn;
    }
    float ss = v0 * v0 + v1 * v1;
#pragma unroll
    for (int off = 32; off > 0; off >>= 1) ss += __shfl_xor(ss, off);
    const float rstd = rsqrtf(ss * (1.0f / 128.0f) + 1e-6f);
    v0 = v0 * rstd * (1.0f + sc[h0]);
    v1 = v1 * rstd * (1.0f + sc[h1]);
    const float p0 = __shfl_xor(v0, 16);
    const float p1 = __shfl_xor(v1, 16);
    if (l < 32) {
      const int i0 = (l < 16) ? h0 : (h0 - 32);
      const float a0 = pos * __expf(-(float)i0 * kfreq);
      const float a1 = pos * __expf(-(float)(i0 + 1) * kfreq);
      const float c0 = cosf(a0), s0 = sinf(a0);
      const float c1 = cosf(a1), s1v = sinf(a1);
      if (l < 16) { v0 = v0 * c0 - p0 * s0; v1 = v1 * c1 - p1 * s1v; }
      else        { v0 = v0 * c0 + p0 * s0; v1 = v1 * c1 + p1 * s1v; }
    }
    if (isq) {
      v0 *= 0.08838834764831843f; v1 *= 0.08838834764831843f;
      qgb[bi + h0] = f2bf(v0); qgb[bi + h1] = f2bf(v1);
    } else {
      kc[bi + h0] = v0; kc[bi + h1] = v1;
      Kb[bi + h0] = f2bf(v0); Kb[bi + h1] = f2bf(v1);
    }
  }
}

// ---------------------------------------------------------------------------
// Flash attention, S^T formulation, XOR-swizzled LDS, single-buffered tiles,
// 2 blocks/CU. grid (32, 16): block (bx, n) handles qt = 31-bx (heavy first).
// qgb: normed q + raw gate bf16 (t,n,256); Kb (t,kh,128); Vt (kh,128,2048).
__global__ __launch_bounds__(256) void attn(
    const ushort* __restrict__ qgb, const ushort* __restrict__ Kb,
    const ushort* __restrict__ Vt, ushort* __restrict__ encb)
{
  __shared__ ushort Ks[16384];  // [s 0..127][h 0..127], 16B chunks ^ (s&15)
  __shared__ ushort Vs[16384];  // [h 0..127][s 0..127], 16B chunks ^ (h&15)
  __shared__ ushort Ps[4 * 2048];   // per-wave [q 0..15][s 0..127], 4-short units ^ lm
  const int tid = threadIdx.x;
  const int w = tid >> 6, l = tid & 63, lq = l >> 4, lm = l & 15;
  const int qt = (int)gridDim.x - 1 - (int)blockIdx.x;  // heavy blocks first
  const int n = blockIdx.y, kh = n >> 2;
  const int qtb = qt * 64;
  const int nst = qt / 2 + 1;

  auto stage = [&](int s0) {
#pragma unroll
    for (int c = 0; c < 8; ++c) {
      const int row = w * 32 + c * 4 + lq;
      const int ch = lm ^ (row & 15);
      const int dst = (w * 32 + c * 4) * 128;
      g2l16(Kb + (size_t)(s0 + row) * 512 + kh * 128 + ch * 8, (AS3 ushort*)Ks + dst);
      g2l16(Vt + (size_t)(kh * 128 + row) * 2048 + s0 + ch * 8, (AS3 ushort*)Vs + dst);
    }
  };

  short8 aq[4];
  {
    const ushort* qb = qgb + ((size_t)(qtb + w * 16 + lm) * NH_ + n) * 256 + lq * 8;
#pragma unroll
    for (int kk = 0; kk < 4; ++kk) aq[kk] = *(const short8*)(qb + kk * 32);
  }
  f32x4 acc[8];
#pragma unroll
  for (int i = 0; i < 8; ++i) acc[i] = (f32x4){0.f, 0.f, 0.f, 0.f};
  float mq = -3.0e38f, lsum = 0.0f;  // softmax state for q = qtb + w*16 + lm

  for (int st = 0; st < nst; ++st) {
    const int s0 = st * 128;
    stage(s0);
    __syncthreads();  // staging visible to all waves

    // S^T = K * Q^T : D[m=s][n=q]
    f32x4 sa[8];
#pragma unroll
    for (int mi = 0; mi < 8; ++mi) sa[mi] = (f32x4){0.f, 0.f, 0.f, 0.f};
#pragma unroll
    for (int kk = 0; kk < 4; ++kk)
#pragma unroll
      for (int mi = 0; mi < 8; ++mi) {
        const short8 ak = *(const short8*)&Ks[(mi * 16 + lm) * 128 + ((kk * 4 + lq) ^ lm) * 8];
        sa[mi] = __builtin_amdgcn_mfma_f32_16x16x32_bf16(ak, aq[kk], sa[mi], 0, 0, 0);
      }
    // causal mask: s > q -> -inf
    if (s0 + 127 > qtb) {
      const int qg_ = qtb + w * 16 + lm;
#pragma unroll
      for (int mi = 0; mi < 8; ++mi)
#pragma unroll
        for (int r = 0; r < 4; ++r)
          if (s0 + mi * 16 + lq * 4 + r > qg_) sa[mi][r] = -3.0e38f;
    }
    // online softmax over s (in-lane 32 vals + 2 shfl levels)
    float mx = sa[0][0];
#pragma unroll
    for (int mi = 0; mi < 8; ++mi)
#pragma unroll
      for (int r = 0; r < 4; ++r) mx = fmaxf(mx, sa[mi][r]);
    mx = fmaxf(mx, __shfl_xor(mx, 16));
    mx = fmaxf(mx, __shfl_xor(mx, 32));
    const float mn = fmaxf(mq, mx);
    const float alpha = __expf(mq - mn);
    mq = mn;
    float sl = 0.0f;
#pragma unroll
    for (int mi = 0; mi < 8; ++mi)
#pragma unroll
      for (int r = 0; r < 4; ++r) {
        const float p = __expf(sa[mi][r] - mn);
        sa[mi][r] = p; sl += p;
      }
    sl += __shfl_xor(sl, 16);
    sl += __shfl_xor(sl, 32);
    lsum = lsum * alpha + sl;

    // P -> per-wave LDS [q][s], bf16, 4-short units, unit index (s/4) ^ lm
#pragma unroll
    for (int mi = 0; mi < 8; ++mi) {
      short4v pw;
#pragma unroll
      for (int r = 0; r < 4; ++r) pw[r] = (short)f2bf(sa[mi][r]);
      *(short4v*)&Ps[w * 2048 + lm * 128 + (((mi * 4 + lq)) ^ lm) * 4] = pw;
    }
    // rescale acc (alpha for q = lq*4+r lives in lane lq*4+r)
    float aP[4];
#pragma unroll
    for (int r = 0; r < 4; ++r) aP[r] = __shfl(alpha, lq * 4 + r);
#pragma unroll
    for (int hi = 0; hi < 8; ++hi) {
      f32x4 a = acc[hi];
#pragma unroll
      for (int r = 0; r < 4; ++r) a[r] *= aP[r];
      acc[hi] = a;
    }
    // O += P V : A = P[q][s] from Ps (k-block mi2 -> s/4 units mi2*8 + lq*2 + {0,1}),
    // B = V[s][h] from Vs (s/8 unit mi2*4 + lq)
#pragma unroll
    for (int mi2 = 0; mi2 < 4; ++mi2) {
      const short4v pa = *(const short4v*)&Ps[w * 2048 + lm * 128 + ((mi2 * 8 + lq * 2 + 0) ^ lm) * 4];
      const short4v pb = *(const short4v*)&Ps[w * 2048 + lm * 128 + ((mi2 * 8 + lq * 2 + 1) ^ lm) * 4];
      const short8 ap = __builtin_shufflevector(pa, pb, 0, 1, 2, 3, 4, 5, 6, 7);
#pragma unroll
      for (int hi = 0; hi < 8; ++hi) {
        const short8 bv = *(const short8*)&Vs[(hi * 16 + lm) * 128 + ((mi2 * 4 + lq) ^ lm) * 8];
        acc[hi] = __builtin_amdgcn_mfma_f32_16x16x32_bf16(ap, bv, acc[hi], 0, 0, 0);
      }
    }
    __syncthreads();  // all reads done before next stage overwrites
  }
  // epilogue: 1/l, sigmoid gate, store (q = qtb + w*16 + lq*4 + r, h = hi*16+lm)
  const float linv = 1.0f / lsum;
  float lP[4];
#pragma unroll
  for (int r = 0; r < 4; ++r) lP[r] = __shfl(linv, lq * 4 + r);
#pragma unroll
  for (int hi = 0; hi < 8; ++hi)
#pragma unroll
    for (int r = 0; r < 4; ++r) {
      const int t = qtb + w * 16 + lq * 4 + r;
      const int h = hi * 16 + lm;
      const float g = bf2f(qgb[((size_t)t * NH_ + n) * 256 + 128 + h]);
      const float o = acc[hi][r] * lP[r] * (1.0f / (1.0f + __expf(-g)));
      encb[((size_t)t * NH_ + n) * 128 + h] = f2bf(o);
    }
}

// ---------------------------------------------------------------------------
extern "C" void kernel_launch(void* const* d_in, const int* in_sizes, int n_in,
                              void* d_out, int out_size, void* d_ws, size_t ws_size,
                              hipStream_t stream)
{
  (void)in_sizes; (void)n_in; (void)out_size; (void)ws_size;
  const float* x0    = (const float*)d_in[0];
  const float* x1    = (const float*)d_in[1];
  const int*   pos   = (const int*)d_in[2];
  const float* qg_w0 = (const float*)d_in[4];
  const float* k_w0  = (const float*)d_in[5];
  const float* v_w0  = (const float*)d_in[6];
  const float* qn0   = (const float*)d_in[7];
  const float* kn0   = (const float*)d_in[8];
  const float* o_w0  = (const float*)d_in[9];
  const float* qg_w1 = (const float*)d_in[10];
  const float* k_w1  = (const float*)d_in[11];
  const float* v_w1  = (const float*)d_in[12];
  const float* qn1   = (const float*)d_in[13];
  const float* kn1   = (const float*)d_in[14];
  const float* o_w1  = (const float*)d_in[15];

  float* out    = (float*)d_out;
  float* kcache = out + (size_t)TT_ * WD_;
  float* vcache = kcache + (size_t)TT_ * KH_ * 128;
  ushort* qsc = (ushort*)d_out;  // out0/out1 region doubles as qg_w0^T scratch

  // ws: wbuf 16M | xb 8M (-> Kb 2M + Vt 2M after projections) | qgb 16M | encb 8M
  ushort* wbuf = (ushort*)d_ws;
  ushort* xb   = wbuf + 8388608;
  ushort* qgb  = xb + 4194304;
  ushort* encb = qgb + 8388608;
  ushort* Kbuf = xb;
  ushort* Vtb  = xb + 1048576;
  ushort* k0t = encb, *k1t = encb + 1048576, *v0t = encb + 2097152, *v1t = encb + 3145728;

  convert_x<<<4096, 256, 0, stream>>>(x0, x1, xb);

  // weight transposes (f32 -> bf16, k-contiguous)
  P4 jq = {{qg_w0, qg_w1, nullptr, nullptr}, {qsc, wbuf, nullptr, nullptr}};
  wtrans4<<<dim3(32, 4, 32), 256, 0, stream>>>(jq, 256, 16);
  P4 jkv = {{k_w0, k_w1, v_w0, v_w1}, {k0t, k1t, v0t, v1t}};
  wtrans4<<<dim3(32, 2, 16), 256, 0, stream>>>(jkv, 128, 4);

  // all projections, one launch
  gemm_proj<<<dim3(40, 16), 256, 0, stream>>>(xb, qsc, wbuf, k0t, k1t, v0t, v1t,
                                              qgb, kcache, vcache);

  // norm + rope (kcache in place -> cached_k; Kb bf16 into xb alias)
  postproc<<<2048, 256, 0, stream>>>(qgb, kcache, Kbuf, pos, qn0, kn0, qn1, kn1);
  // Vt (kh*128+h, t) bf16 from vcache
  P4 jv = {{vcache, nullptr, nullptr, nullptr}, {Vtb, nullptr, nullptr, nullptr}};
  wtrans4<<<dim3(32, 8, 1), 256, 0, stream>>>(jv, 512, 1);

  attn<<<dim3(32, 16), 256, 0, stream>>>(qgb, Kbuf, Vtb, encb);

  // output projection
  P4 jo = {{o_w0, o_w1, nullptr, nullptr}, {wbuf, wbuf + 4194304, nullptr, nullptr}};
  wtrans4<<<dim3(32, 32, 2), 256, 0, stream>>>(jo, 2048, 1);
  gemm_out<<<dim3(16, 16), 256, 0, stream>>>(encb, wbuf, wbuf + 4194304, out);
}